// Round 3
// baseline (141.047 us; speedup 1.0000x reference)
//
#include <hip/hip_runtime.h>

// MechanicsPINN: residual = EI*biharm(f) + GC*lap(f) + KC*f - P,
// f = MLP(x) 2->256->512->1024->65536, B=64, grid 256x256. All inputs fp32.
// Round 3: main GEMM (M=64,N=65536,K=1024) bf16 MFMA, LDS-free.
// Wave owns 16 n-cols x all 64 m -> one B-fragment feeds 4 MFMAs; B goes
// global->reg->bf16 exactly once per element (no LDS, no barriers).

#define BATCH 64
#define NPIX 65536

typedef __attribute__((ext_vector_type(8))) short short8_t;  // bf16 x8 (4 VGPR)
typedef __attribute__((ext_vector_type(4))) float f32x4;

__device__ __forceinline__ short f2bf(float x) {  // fp32 -> bf16 RNE
    unsigned u = __float_as_uint(x);
    unsigned r = (u + 0x7fffu + ((u >> 16) & 1u)) >> 16;
    return (short)r;
}

// ---------------- Layer 1: h1 = relu(x @ W1 + b1), K=2 ----------------
__global__ void k_l1(const float* __restrict__ x, const float* __restrict__ W1,
                     const float* __restrict__ b1, float* __restrict__ h1) {
    int gid = blockIdx.x * 256 + threadIdx.x;   // 64*256 threads
    int m = gid >> 8, n = gid & 255;
    float v = x[m * 2 + 0] * W1[n] + x[m * 2 + 1] * W1[256 + n] + b1[n];
    h1[gid] = v > 0.f ? v : 0.f;
}

// ------------- Generic small layer: out = relu(A @ W + b) -------------
// A [64][K], W [K][N]. 16x16 output tile per block. If out_bf != null,
// writes bf16 ONLY (used for h3, consumed by the MFMA GEMM).
__global__ void k_layer(const float* __restrict__ A, const float* __restrict__ Wt,
                        const float* __restrict__ bias, float* __restrict__ out,
                        short* __restrict__ out_bf, int K, int N) {
    __shared__ float As[16][64];
    __shared__ float Ws[64][16];
    int tid = threadIdx.x;
    int tn = tid & 15, tm = tid >> 4;
    int n0 = blockIdx.x * 16, m0 = blockIdx.y * 16;
    float acc = 0.f;
    for (int k0 = 0; k0 < K; k0 += 64) {
#pragma unroll
        for (int j = 0; j < 4; ++j) {          // stage A 16x64
            int e = j * 256 + tid;
            As[e >> 6][e & 63] = A[(m0 + (e >> 6)) * K + k0 + (e & 63)];
        }
#pragma unroll
        for (int j = 0; j < 4; ++j) {          // stage W 64x16
            int e = j * 256 + tid;
            Ws[e >> 4][e & 15] = Wt[(k0 + (e >> 4)) * N + n0 + (e & 15)];
        }
        __syncthreads();
#pragma unroll
        for (int k = 0; k < 64; ++k)
            acc += As[tm][k] * Ws[k][tn];
        __syncthreads();
    }
    acc += bias[n0 + tn];
    acc = acc > 0.f ? acc : 0.f;               // relu
    if (out_bf)
        out_bf[(m0 + tm) * N + n0 + tn] = f2bf(acc);
    else
        out[(m0 + tm) * N + n0 + tn] = acc;
}

// ---------- Main GEMM: f = h3b @ W4 + b4 (bf16 MFMA, M=64,N=65536,K=1024) ----
// 256 threads (4 waves), block n-chunk = 64 cols, wave = 16 cols x all 64 m.
// B-fragment: lane (col=lane&15, g=lane>>4) loads W[g*8+j][col] j=0..7 from
// GLOBAL (one instr = 4x64B contiguous row segments), converts to bf16 once.
// A (h3 bf16, 128KB, L2-resident): 4x 16B fragments per step. No LDS.
__global__ __launch_bounds__(256) void k_gemm_mfma(
        const short* __restrict__ A,     // h3 bf16 [64][1024]
        const float* __restrict__ W,     // W4 fp32 [1024][65536]
        const float* __restrict__ bias,  // [65536]
        float* __restrict__ f) {         // [64][65536]
    const int tid = threadIdx.x;
    const int lane = tid & 63;
    const int w = tid >> 6;
    const int lr = lane & 15;
    const int g = lane >> 4;
    const int col = blockIdx.x * 64 + w * 16 + lr;

    f32x4 acc[4] = {{0.f, 0.f, 0.f, 0.f}, {0.f, 0.f, 0.f, 0.f},
                    {0.f, 0.f, 0.f, 0.f}, {0.f, 0.f, 0.f, 0.f}};

    const float* wp = W + (size_t)(g * 8) * NPIX + col;  // k = g*8+j, + 32/step
    const short* ap = A + g * 8;                          // + row*1024 + s*32

    float bcur[8];
#pragma unroll
    for (int j = 0; j < 8; ++j) bcur[j] = wp[(size_t)j * NPIX];

    for (int s = 0; s < 32; ++s) {
        float bnxt[8];
        if (s < 31) {
            const float* wn = wp + (size_t)32 * NPIX;
#pragma unroll
            for (int j = 0; j < 8; ++j) bnxt[j] = wn[(size_t)j * NPIX];
        }
        short8_t bf;
#pragma unroll
        for (int j = 0; j < 8; ++j) bf[j] = f2bf(bcur[j]);
#pragma unroll
        for (int mt = 0; mt < 4; ++mt) {
            short8_t af = *(const short8_t*)(ap + (mt * 16 + lr) * 1024 + s * 32);
            acc[mt] = __builtin_amdgcn_mfma_f32_16x16x32_bf16(af, bf, acc[mt], 0, 0, 0);
        }
        wp += (size_t)32 * NPIX;
#pragma unroll
        for (int j = 0; j < 8; ++j) bcur[j] = bnxt[j];
    }

    // C/D layout: col = lane&15, row = (lane>>4)*4 + reg
    float bb = bias[col];
#pragma unroll
    for (int mt = 0; mt < 4; ++mt) {
        int rowb = mt * 16 + g * 4;
#pragma unroll
        for (int r = 0; r < 4; ++r)
            f[(size_t)(rowb + r) * NPIX + col] = acc[mt][r] + bb;
    }
}

// --------------------------- Stencil ---------------------------
// residual = biharm + lap + f - P; reflect-1 index reflection.
#define ROWS 16
__device__ __forceinline__ int rfl(int i) {
    return i < 0 ? -i : (i > 255 ? 510 - i : i);
}
__global__ void k_stencil(const float* __restrict__ f, const float* __restrict__ P,
                          float* __restrict__ out) {
    __shared__ float fs[ROWS + 4][256];
    int x = threadIdx.x;
    int y0 = blockIdx.x * ROWS;
    int b = blockIdx.y;
    const float* fb = f + (size_t)b * NPIX;
    for (int t = 0; t < ROWS + 4; ++t) {
        int gy = rfl(y0 - 2 + t);
        fs[t][x] = fb[gy * 256 + x];
    }
    __syncthreads();

    int xm = x == 0 ? 1 : x - 1;
    int xp = x == 255 ? 254 : x + 1;

    auto lapAt = [&](int j, int i) {
        int s = j - y0 + 2;
        int sm = rfl(j - 1) - y0 + 2;
        int sp = rfl(j + 1) - y0 + 2;
        int im = i == 0 ? 1 : i - 1;
        int ip = i == 255 ? 254 : i + 1;
        float c = fs[s][i];
        return (fs[sm][i] - 2.f * c + fs[sp][i]) + (fs[s][im] - 2.f * c + fs[s][ip]);
    };

    for (int r = 0; r < ROWS; ++r) {
        int y = y0 + r;
        float lc = lapAt(y, x);
        float lym = lapAt(rfl(y - 1), x);
        float lyp = lapAt(rfl(y + 1), x);
        float lxm = lapAt(y, xm);
        float lxp = lapAt(y, xp);
        float bih = (lym - 2.f * lc + lyp) + (lxm - 2.f * lc + lxp);
        float fc = fs[r + 2][x];
        size_t idx = (size_t)b * NPIX + y * 256 + x;
        out[idx] = bih + lc + fc - P[idx];
    }
}

extern "C" void kernel_launch(void* const* d_in, const int* in_sizes, int n_in,
                              void* d_out, int out_size, void* d_ws, size_t ws_size,
                              hipStream_t stream) {
    const float* x  = (const float*)d_in[0];
    const float* P  = (const float*)d_in[1];
    const float* W1 = (const float*)d_in[2];
    const float* b1 = (const float*)d_in[3];
    const float* W2 = (const float*)d_in[4];
    const float* b2 = (const float*)d_in[5];
    const float* W3 = (const float*)d_in[6];
    const float* b3 = (const float*)d_in[7];
    const float* W4 = (const float*)d_in[8];
    const float* b4 = (const float*)d_in[9];
    float* out = (float*)d_out;

    char* ws = (char*)d_ws;
    float* h1  = (float*)(ws);                      // 64*256*4  = 64 KB
    float* h2  = (float*)(ws + (64 << 10));         // 64*512*4  = 128 KB
    short* h3b = (short*)(ws + (192 << 10));        // 64*1024*2 = 128 KB (bf16)
    float* f   = (float*)(ws + (320 << 10));        // 64*65536*4 = 16 MB

    k_l1<<<64, 256, 0, stream>>>(x, W1, b1, h1);
    k_layer<<<dim3(512 / 16, 4), 256, 0, stream>>>(h1, W2, b2, h2, nullptr, 256, 512);
    k_layer<<<dim3(1024 / 16, 4), 256, 0, stream>>>(h2, W3, b3, nullptr, h3b, 512, 1024);
    k_gemm_mfma<<<NPIX / 64, 256, 0, stream>>>(h3b, W4, b4, f);
    k_stencil<<<dim3(256 / ROWS, BATCH), 256, 0, stream>>>(f, P, out);
}

// Round 4
// 112.190 us; speedup vs baseline: 1.2572x; 1.2572x over previous
//
#include <hip/hip_runtime.h>

// MechanicsPINN: residual = EI*biharm(f) + GC*lap(f) + KC*f - P,
// f = MLP(x) 2->256->512->1024->65536, B=64, grid 256x256. All inputs fp32.
// Round 4: main GEMM (M=64,N=65536,K=1024) bf16 MFMA.
//  - global_load_lds(16B) staging of W tiles (proven HBM-efficient, R2)
//  - wave = 16 n-cols x all 64 m  -> each W element LDS-read+f2bf exactly once
//  - 3-buffer / 2-deep pipeline, counted vmcnt(6), one barrier per K-step
//  - XOR bank swizzle (col bit4 ^= k bit3) applied on the global source,
//    undone at the LDS read -> 2-way (free) bank access.

#define BATCH 64
#define NPIX 65536

typedef __attribute__((ext_vector_type(8))) short short8_t;  // bf16 x8 (4 VGPR)
typedef __attribute__((ext_vector_type(4))) float f32x4;

__device__ __forceinline__ short f2bf(float x) {  // fp32 -> bf16 RNE
    unsigned u = __float_as_uint(x);
    unsigned r = (u + 0x7fffu + ((u >> 16) & 1u)) >> 16;
    return (short)r;
}

// ---------------- Layer 1: h1 = relu(x @ W1 + b1), K=2 ----------------
__global__ void k_l1(const float* __restrict__ x, const float* __restrict__ W1,
                     const float* __restrict__ b1, float* __restrict__ h1) {
    int gid = blockIdx.x * 256 + threadIdx.x;   // 64*256 threads
    int m = gid >> 8, n = gid & 255;
    float v = x[m * 2 + 0] * W1[n] + x[m * 2 + 1] * W1[256 + n] + b1[n];
    h1[gid] = v > 0.f ? v : 0.f;
}

// ------------- Generic small layer: out = relu(A @ W + b) -------------
__global__ void k_layer(const float* __restrict__ A, const float* __restrict__ Wt,
                        const float* __restrict__ bias, float* __restrict__ out,
                        short* __restrict__ out_bf, int K, int N) {
    __shared__ float As[16][64];
    __shared__ float Ws[64][16];
    int tid = threadIdx.x;
    int tn = tid & 15, tm = tid >> 4;
    int n0 = blockIdx.x * 16, m0 = blockIdx.y * 16;
    float acc = 0.f;
    for (int k0 = 0; k0 < K; k0 += 64) {
#pragma unroll
        for (int j = 0; j < 4; ++j) {          // stage A 16x64
            int e = j * 256 + tid;
            As[e >> 6][e & 63] = A[(m0 + (e >> 6)) * K + k0 + (e & 63)];
        }
#pragma unroll
        for (int j = 0; j < 4; ++j) {          // stage W 64x16
            int e = j * 256 + tid;
            Ws[e >> 4][e & 15] = Wt[(k0 + (e >> 4)) * N + n0 + (e & 15)];
        }
        __syncthreads();
#pragma unroll
        for (int k = 0; k < 64; ++k)
            acc += As[tm][k] * Ws[k][tn];
        __syncthreads();
    }
    acc += bias[n0 + tn];
    acc = acc > 0.f ? acc : 0.f;               // relu
    if (out_bf)
        out_bf[(m0 + tm) * N + n0 + tn] = f2bf(acc);
    else
        out[(m0 + tm) * N + n0 + tn] = acc;
}

// ---------- Main GEMM: f = h3b @ W4 + b4 (bf16 MFMA, M=64,N=65536,K=1024) ----
__global__ __launch_bounds__(512) void k_gemm_mfma(
        const short* __restrict__ A,     // h3 bf16 [64][1024]
        const float* __restrict__ W,     // W4 fp32 [1024][65536]
        const float* __restrict__ bias,  // [65536]
        float* __restrict__ f) {         // [64][65536]
    __shared__ float Wl[3][32 * 128];    // 3 x 16KB, [k][n] fp32, swizzled
    const int tid = threadIdx.x;
    const int lane = tid & 63;
    const int w = tid >> 6;              // 8 waves
    const int lr = lane & 15;
    const int g = lane >> 4;             // k-group 0..3
    const int n0 = blockIdx.x * 128;
    const int colw = w * 16 + lr;                 // 0..127 in block
    const int colsw = colw ^ ((g & 1) << 4);      // swizzled read col

    f32x4 acc[4] = {{0.f, 0.f, 0.f, 0.f}, {0.f, 0.f, 0.f, 0.f},
                    {0.f, 0.f, 0.f, 0.f}, {0.f, 0.f, 0.f, 0.f}};

    // A-frag base: element j of frag (mt,s) = A[(mt*16+lr)*1024 + s*32 + g*8 + j]
    const short* ap = A + lr * 1024 + g * 8;

    // stage one 32x128 fp32 W tile: 1024 16B chunks; LDS dest linear
    // (wave-uniform base + lane*16), global source pre-swizzled (col^16 if k&8)
    auto stage = [&](int buf, int k0) {
#pragma unroll
        for (int i = 0; i < 2; ++i) {
            int c = (i * 8 + w) * 64 + lane;
            int k = c >> 5;
            int c4 = (c & 31) * 4;
            int csw = c4 ^ ((k & 8) << 1);        // ^16 when k bit3 set
            const float* src = W + (size_t)(k0 + k) * NPIX + n0 + csw;
            __builtin_amdgcn_global_load_lds(
                (const __attribute__((address_space(1))) void*)src,
                (__attribute__((address_space(3))) void*)(&Wl[buf][(i * 8 + w) * 256]),
                16, 0, 0);
        }
    };

    short8_t aC[4], aN[4];

    stage(0, 0);
    stage(1, 32);
#pragma unroll
    for (int mt = 0; mt < 4; ++mt)
        aC[mt] = *(const short8_t*)(ap + mt * 16384);          // s = 0

    auto compute = [&](int cur, short8_t* aa) {
        // k = g*8+j -> LDS float idx (g*8+j)*128 + colsw = g*1024 + colsw + j*128
        const float* wb = &Wl[cur][g * 1024 + colsw];
        short8_t bf;
#pragma unroll
        for (int j = 0; j < 8; ++j)
            bf[j] = f2bf(wb[j * 128]);
#pragma unroll
        for (int mt = 0; mt < 4; ++mt)
            acc[mt] = __builtin_amdgcn_mfma_f32_16x16x32_bf16(aa[mt], bf, acc[mt], 0, 0, 0);
    };

    // steady state: outstanding at wait = stage(s+1):2 + Apre(s):4 = 6
    for (int s = 0; s <= 29; ++s) {
        asm volatile("s_waitcnt vmcnt(6)" ::: "memory");
        asm volatile("s_barrier" ::: "memory");
        stage((s + 2) % 3, (s + 2) * 32);
#pragma unroll
        for (int mt = 0; mt < 4; ++mt)
            aN[mt] = *(const short8_t*)(ap + mt * 16384 + (s + 1) * 32);
        compute(s % 3, aC);
#pragma unroll
        for (int mt = 0; mt < 4; ++mt) aC[mt] = aN[mt];
    }
    // s = 30: no stage(32)
    asm volatile("s_waitcnt vmcnt(6)" ::: "memory");
    asm volatile("s_barrier" ::: "memory");
#pragma unroll
    for (int mt = 0; mt < 4; ++mt)
        aN[mt] = *(const short8_t*)(ap + mt * 16384 + 31 * 32);
    compute(0, aC);
#pragma unroll
    for (int mt = 0; mt < 4; ++mt) aC[mt] = aN[mt];
    // s = 31: only Apre(31):4 may remain
    asm volatile("s_waitcnt vmcnt(4)" ::: "memory");
    asm volatile("s_barrier" ::: "memory");
    compute(1, aC);

    // C/D layout: col = lane&15, row = (lane>>4)*4 + reg
    const int col = n0 + colw;
    float bb = bias[col];
#pragma unroll
    for (int mt = 0; mt < 4; ++mt) {
        int rowb = mt * 16 + g * 4;
#pragma unroll
        for (int r = 0; r < 4; ++r)
            f[(size_t)(rowb + r) * NPIX + col] = acc[mt][r] + bb;
    }
}

// --------------------------- Stencil ---------------------------
// residual = biharm + lap + f - P; reflect-1 index reflection.
#define ROWS 16
__device__ __forceinline__ int rfl(int i) {
    return i < 0 ? -i : (i > 255 ? 510 - i : i);
}
__global__ void k_stencil(const float* __restrict__ f, const float* __restrict__ P,
                          float* __restrict__ out) {
    __shared__ float fs[ROWS + 4][256];
    int x = threadIdx.x;
    int y0 = blockIdx.x * ROWS;
    int b = blockIdx.y;
    const float* fb = f + (size_t)b * NPIX;
    for (int t = 0; t < ROWS + 4; ++t) {
        int gy = rfl(y0 - 2 + t);
        fs[t][x] = fb[gy * 256 + x];
    }
    __syncthreads();

    int xm = x == 0 ? 1 : x - 1;
    int xp = x == 255 ? 254 : x + 1;

    auto lapAt = [&](int j, int i) {
        int s = j - y0 + 2;
        int sm = rfl(j - 1) - y0 + 2;
        int sp = rfl(j + 1) - y0 + 2;
        int im = i == 0 ? 1 : i - 1;
        int ip = i == 255 ? 254 : i + 1;
        float c = fs[s][i];
        return (fs[sm][i] - 2.f * c + fs[sp][i]) + (fs[s][im] - 2.f * c + fs[s][ip]);
    };

    for (int r = 0; r < ROWS; ++r) {
        int y = y0 + r;
        float lc = lapAt(y, x);
        float lym = lapAt(rfl(y - 1), x);
        float lyp = lapAt(rfl(y + 1), x);
        float lxm = lapAt(y, xm);
        float lxp = lapAt(y, xp);
        float bih = (lym - 2.f * lc + lyp) + (lxm - 2.f * lc + lxp);
        float fc = fs[r + 2][x];
        size_t idx = (size_t)b * NPIX + y * 256 + x;
        out[idx] = bih + lc + fc - P[idx];
    }
}

extern "C" void kernel_launch(void* const* d_in, const int* in_sizes, int n_in,
                              void* d_out, int out_size, void* d_ws, size_t ws_size,
                              hipStream_t stream) {
    const float* x  = (const float*)d_in[0];
    const float* P  = (const float*)d_in[1];
    const float* W1 = (const float*)d_in[2];
    const float* b1 = (const float*)d_in[3];
    const float* W2 = (const float*)d_in[4];
    const float* b2 = (const float*)d_in[5];
    const float* W3 = (const float*)d_in[6];
    const float* b3 = (const float*)d_in[7];
    const float* W4 = (const float*)d_in[8];
    const float* b4 = (const float*)d_in[9];
    float* out = (float*)d_out;

    char* ws = (char*)d_ws;
    float* h1  = (float*)(ws);                      // 64*256*4  = 64 KB
    float* h2  = (float*)(ws + (64 << 10));         // 64*512*4  = 128 KB
    short* h3b = (short*)(ws + (192 << 10));        // 64*1024*2 = 128 KB (bf16)
    float* f   = (float*)(ws + (320 << 10));        // 64*65536*4 = 16 MB

    k_l1<<<64, 256, 0, stream>>>(x, W1, b1, h1);
    k_layer<<<dim3(512 / 16, 4), 256, 0, stream>>>(h1, W2, b2, h2, nullptr, 256, 512);
    k_layer<<<dim3(1024 / 16, 4), 256, 0, stream>>>(h2, W3, b3, nullptr, h3b, 512, 1024);
    k_gemm_mfma<<<NPIX / 128, 512, 0, stream>>>(h3b, W4, b4, f);
    k_stencil<<<dim3(256 / ROWS, BATCH), 256, 0, stream>>>(f, P, out);
}